// Round 11
// baseline (939.637 us; speedup 1.0000x reference)
//
#include <hip/hip_runtime.h>
#include <math.h>

#define BRR 512
#define LLL 64
#define KKK 16
#define EEE 64
#define CC2 8
#define PPP 1024
#define BN_EPS 1e-5f
#define NSTRIPE 16

__device__ __forceinline__ float relu_f(float v){ return v>0.f?v:0.f; }
// Row-padded W1 layout: stride 68 + 4-float stagger per 8-row octet.
// Monotone (no overlap: gaps 68/72; max 63*68+28+63=4375<4384) and the wave's
// 8 og-rows (r=og*8+j) land on distinct 4-bank groups (offset 4*og mod 32).
// NOTE: previous (((r>>2)&7)<<2) stagger WRAPPED at r=32 -> rows 31/32 overlapped.
__device__ __forceinline__ int lds_row(int r){ return r*68 + (((r>>3)&7)<<2); }

// ---- d_ws float layout ----
#define OFF_HBL  0u          // [(b*64+l)*8+c2]            262144
#define OFF_HBK  262144u     // [(b*16+k)*8+c2]             65536
#define OFF_Y0   327680u     // [b*1024 + k*64+c]          524288
#define OFF_X1   851968u     // [(b*64+l)*64+c] M0L->X1   2097152
#define OFF_Y1   2949120u    // [b*1024 + k*64+o] M0K->Y1  524288
#define OFF_X2   3473408u    // [(b*64+l)*8+o2]            262144
#define OFF_Y2   3735552u    // [(b*16+k)*8+o2] atomic      65536
#define OFF_SUM0 3801088u
#define OFF_SSQ0 3802112u
#define OFF_SUM1 3803136u
#define OFF_SSQ1 3804160u
#define OFF_S0   3805184u
#define OFF_T0   3805248u
#define OFF_S1   3805312u
#define OFF_T1   3805376u
#define WS_FLOATS 3805440u   // 15,221,760 bytes

// ---------------------------------------------------------------------------
// K0: zero atomic regions (Y2 + 4 stat arrays, contiguous 69632 floats).
__global__ void k_zero(float4* __restrict__ p, int n4){
  int t = blockIdx.x*256 + threadIdx.x;
  if (t < n4) p[t] = make_float4(0.f,0.f,0.f,0.f);
}

// K1: per-b prep. HbL,HbK,y0,M0K,M0L + BN0 channel sums. All inputs f32.
__global__ __launch_bounds__(256) void k_prep(const float* __restrict__ Hr,
                                              const float* __restrict__ Hi,
                                              const float* __restrict__ P40,
                                              float* __restrict__ ws){
  __shared__ float sm[9344];
  int b = blockIdx.x, tid = threadIdx.x;
  const float* hrg = Hr + (size_t)b*4096;
  const float* hig = Hi + (size_t)b*4096;
  for (int t=tid;t<4096;t+=256){ sm[t]=hrg[t]; sm[4096+t]=hig[t]; }
  for (int t=tid;t<512;t+=256){ int c=t&63,j=t>>6; sm[8192+j*64+c]=P40[c*8+j]; }
  __syncthreads();
  for (int t=tid;t<512;t+=256){ int l=t>>3,c2=t&7;          // HbL [8704,9216)
    const float* src=sm+((c2<4)?0:4096); int u=c2&3;
    float s=0.f;
    #pragma unroll
    for(int k=0;k<16;++k) s+=src[(l*16+k)*4+u];
    sm[8704+t]=s*(1.f/16.f); }
  for (int t=tid;t<128;t+=256){ int k=t>>3,c2=t&7;          // HbK [9216,9344)
    const float* src=sm+((c2<4)?0:4096); int u=c2&3;
    float s=0.f;
    for(int l=0;l<64;++l) s+=src[(l*16+k)*4+u];
    sm[9216+t]=s*(1.f/64.f); }
  __syncthreads();
  for (int t=tid;t<1024;t+=256){ int k=t>>6,c=t&63; float s=0.f;   // y0 [4096,5120)
    #pragma unroll
    for(int j=0;j<8;++j) s+=sm[8192+j*64+c]*sm[9216+k*8+j];
    sm[4096+t]=0.1f*s; }
  for (int t=tid;t<4096;t+=256){ int l=t>>6,c=t&63; float s=0.f;   // x0 [0,4096)
    #pragma unroll
    for(int j=0;j<8;++j) s+=sm[8192+j*64+c]*sm[8704+l*8+j];
    sm[t]=0.1f*s; }
  __syncthreads();
  for (int t=tid;t<1024;t+=256){ int c=t&63; float yv=sm[4096+t]; float s=0.f;  // M0K [5120,6144)
    for(int l=0;l<64;++l) s+=relu_f(sm[l*64+c]+yv);
    sm[5120+t]=s*(1.f/64.f); }
  float ssum=0.f, ssq=0.f;                       // channel c = tid&63 (stride 256 preserves it)
  for (int t=tid;t<4096;t+=256){ int c=t&63; float xv=sm[t]; float s=0.f;
    #pragma unroll
    for(int k=0;k<16;++k){ float v=relu_f(xv+sm[4096+k*64+c]); s+=v; ssq+=v*v; }
    ssum+=s;
    ws[OFF_X1+(size_t)b*4096+t]=s*(1.f/16.f); }  // M0L
  __syncthreads();
  sm[6144+tid]=ssum; sm[6400+tid]=ssq;
  __syncthreads();
  if (tid<64){
    float ts =sm[6144+tid]+sm[6208+tid]+sm[6272+tid]+sm[6336+tid];
    float tss=sm[6400+tid]+sm[6464+tid]+sm[6528+tid]+sm[6592+tid];
    int stripe = b & (NSTRIPE-1);
    atomicAdd(&ws[OFF_SUM0+stripe*64+tid], ts);
    atomicAdd(&ws[OFF_SSQ0+stripe*64+tid], tss);
  }
  for (int t=tid;t<512;t+=256)  ws[OFF_HBL+(size_t)b*512+t]=sm[8704+t];
  for (int t=tid;t<128;t+=256)  ws[OFF_HBK+(size_t)b*128+t]=sm[9216+t];
  for (int t=tid;t<1024;t+=256) ws[OFF_Y0+(size_t)b*1024+t]=sm[4096+t];
  for (int t=tid;t<1024;t+=256) ws[OFF_Y1+(size_t)b*1024+t]=sm[5120+t];   // M0K
}

// K2: finalize BN -> s,t.
__global__ void k_bn(float* __restrict__ ws, const float* __restrict__ g_,
                     const float* __restrict__ b_, unsigned sumOff, unsigned outOff){
  int tid = threadIdx.x;
  if (tid < 64){
    float s=0.f, ss=0.f;
    for (int i=0;i<NSTRIPE;++i){ s+=ws[sumOff+i*64+tid]; ss+=ws[sumOff+1024+i*64+tid]; }
    const float invN = 1.0f/((float)BRR*LLL*KKK);
    float mu=s*invN, var=ss*invN-mu*mu;
    float sc = g_[tid]/sqrtf(var+BN_EPS);
    ws[outOff+tid]=sc;
    ws[outOff+64+tid]=b_[tid]-mu*sc;
  }
}

// K3: X1/Y1 in place over M0L/M0K.
__global__ __launch_bounds__(256) void k_xy1(float* __restrict__ ws,
                                             const float* __restrict__ P21,
                                             const float* __restrict__ P41){
  __shared__ float wt[4096], p41[512], mrow[1024], hbs[128], s0l[64], t0l[64];
  int bx = blockIdx.x, tid = threadIdx.x;
  for (int t=tid;t<4096;t+=256) wt[t] = 2.0f*P21[(t&63)*64 + (t>>6)];  // [c*64+o]
  for (int t=tid;t<512;t+=256)  p41[t] = P41[t];                        // [o*8+j]
  if (tid<64){ s0l[tid]=ws[OFF_S0+tid]; t0l[tid]=ws[OFF_T0+tid]; }
  bool isX = bx < 2048;
  int row0 = isX ? bx*16 : (bx-2048)*16;
  if (isX){
    for (int t=tid;t<1024;t+=256) mrow[t] = ws[OFF_X1+(size_t)row0*64+t];
    if (tid<128) hbs[tid] = ws[OFF_HBL+(size_t)row0*8+tid];
  } else {
    for (int t=tid;t<1024;t+=256) mrow[t] = ws[OFF_Y1+(size_t)row0*64+t];
    if (tid<128) hbs[tid] = ws[OFF_HBK+(size_t)row0*8+tid];
  }
  __syncthreads();
  for (int t=tid;t<1024;t+=256){ int c=t&63; mrow[t]=s0l[c]*mrow[t]+t0l[c]; }
  __syncthreads();
  int r4 = tid>>6, o = tid&63;
  #pragma unroll
  for (int rr=0;rr<4;++rr){
    int rl = rr*4 + r4;
    float s=0.f;
    for (int c=0;c<64;++c) s += wt[c*64+o]*mrow[rl*64+c];
    float s2=0.f;
    #pragma unroll
    for (int j=0;j<8;++j) s2 += p41[o*8+j]*hbs[rl*8+j];
    float res = s + 0.1f*s2;
    if (isX) ws[OFF_X1+(size_t)(row0+rl)*64+o] = res;
    else     ws[OFF_Y1+(size_t)(row0+rl)*64+o] = res;
  }
}

// ---- T1 tile recompute. Thread (og,pg): channels c0=og*8..+7, l=pblk*8+lloc, k=(pg&3)*4+i.
#define T_W1   0
#define T_X08  4384
#define T_Y0   4896
#define T_X1   5984
#define T_Y1   6496
#define T_S0   7520
#define T_T0   7584
#define T_P4T0 7648
#define T_HB8  8160
#define T_END  8224

__device__ void t1_tile(float* sm, const float* __restrict__ ws,
                        const float* __restrict__ P11, const float* __restrict__ P40,
                        int b, int pblk, int tid,
                        float acc[8][4], int og, int pg, int lloc, int c0){
  for (int t=tid;t<4096;t+=256){ int o=t>>6,c=t&63; sm[T_W1+lds_row(o)+c]=2.0f*P11[t]; }
  for (int t=tid;t<1024;t+=256){ int k=t>>6,c=t&63; sm[T_Y0+k*68+c]=ws[OFF_Y0+(size_t)b*1024+t]; }
  for (int t=tid;t<512;t+=256)  sm[T_X1+t]=ws[OFF_X1+((size_t)b*64+pblk*8)*64+t];
  for (int t=tid;t<1024;t+=256) sm[T_Y1+t]=ws[OFF_Y1+(size_t)b*1024+t];
  for (int t=tid;t<512;t+=256){ int c=t&63,j=t>>6; sm[T_P4T0+j*64+c]=P40[c*8+j]; }
  if (tid<64){ sm[T_S0+tid]=ws[OFF_S0+tid]; sm[T_T0+tid]=ws[OFF_T0+tid]; }
  else if (tid<128){ int t2=tid-64; sm[T_HB8+t2]=ws[OFF_HBL+((size_t)b*64+pblk*8)*8+t2]; }
  __syncthreads();
  for (int e=tid;e<512;e+=256){ int l=e>>6,c=e&63; float s=0.f;
    #pragma unroll
    for(int j=0;j<8;++j) s += sm[T_P4T0+j*64+c]*sm[T_HB8+l*8+j];
    sm[T_X08+e]=0.1f*s; }
  __syncthreads();
  {
    float xb[8];
    *(float4*)&xb[0] = *(const float4*)&sm[T_X1 + lloc*64 + c0];
    *(float4*)&xb[4] = *(const float4*)&sm[T_X1 + lloc*64 + c0 + 4];
    #pragma unroll
    for (int i=0;i<4;++i){
      int k=(pg&3)*4+i;
      float yb[8];
      *(float4*)&yb[0] = *(const float4*)&sm[T_Y1 + k*64 + c0];
      *(float4*)&yb[4] = *(const float4*)&sm[T_Y1 + k*64 + c0 + 4];
      #pragma unroll
      for (int j=0;j<8;++j) acc[j][i]=xb[j]+yb[j];
    }
  }
  #pragma unroll
  for (int c4=0;c4<16;++c4){
    float4 xr  = *(const float4*)&sm[T_X08 + lloc*64 + c4*4];
    float4 s0v = *(const float4*)&sm[T_S0 + c4*4];
    float4 t0v = *(const float4*)&sm[T_T0 + c4*4];
    float4 aa[4];
    #pragma unroll
    for (int i=0;i<4;++i){
      int k=(pg&3)*4+i;
      float4 yr = *(const float4*)&sm[T_Y0 + k*68 + c4*4];
      aa[i].x = s0v.x*relu_f(xr.x+yr.x)+t0v.x;
      aa[i].y = s0v.y*relu_f(xr.y+yr.y)+t0v.y;
      aa[i].z = s0v.z*relu_f(xr.z+yr.z)+t0v.z;
      aa[i].w = s0v.w*relu_f(xr.w+yr.w)+t0v.w;
    }
    #pragma unroll
    for (int j=0;j<8;++j){
      float4 w = *(const float4*)&sm[T_W1 + lds_row(c0+j) + c4*4];
      #pragma unroll
      for (int i=0;i<4;++i)
        acc[j][i] += w.x*aa[i].x + w.y*aa[i].y + w.z*aa[i].z + w.w*aa[i].w;
    }
  }
  #pragma unroll
  for (int j=0;j<8;++j)
    #pragma unroll
    for (int i=0;i<4;++i) acc[j][i] = relu_f(acc[j][i]);
}

// K4: tile pass #1 -> BN1 sums per channel.
__global__ __launch_bounds__(256) void k_stats1(float* __restrict__ ws,
                                                const float* __restrict__ P11,
                                                const float* __restrict__ P40){
  __shared__ float sm[12448];   // stats: s [8224,10336) pad-33, q [10336,12448)
  int bid=blockIdx.x, b=bid>>3, pblk=bid&7, tid=threadIdx.x;
  int og=tid&7, pg=tid>>3, lloc=pg>>2, c0=og*8;
  float acc[8][4];
  t1_tile(sm, ws, P11, P40, b, pblk, tid, acc, og, pg, lloc, c0);
  #pragma unroll
  for (int j=0;j<8;++j){
    float sj=acc[j][0]+acc[j][1]+acc[j][2]+acc[j][3];
    float qj=acc[j][0]*acc[j][0]+acc[j][1]*acc[j][1]+acc[j][2]*acc[j][2]+acc[j][3]*acc[j][3];
    sm[8224 + (c0+j)*33 + pg] = sj;
    sm[10336 + (c0+j)*33 + pg] = qj;
  }
  __syncthreads();
  if (tid<64){
    float ts=0.f, tss=0.f;
    for (int g=0; g<32; ++g){ ts += sm[8224+tid*33+g]; tss += sm[10336+tid*33+g]; }
    int stripe = b & (NSTRIPE-1);
    atomicAdd(&ws[OFF_SUM1+stripe*64+tid], ts);
    atomicAdd(&ws[OFF_SSQ1+stripe*64+tid], tss);
  }
}

// K5: tile pass #2 -> X2 (direct) / Y2 (atomic partials over pblk).
__global__ __launch_bounds__(256) void k_xy2(float* __restrict__ ws,
                                             const float* __restrict__ P11,
                                             const float* __restrict__ P40,
                                             const float* __restrict__ P22,
                                             const float* __restrict__ P42){
  __shared__ float sm[12480];
  int bid=blockIdx.x, b=bid>>3, pblk=bid&7, tid=threadIdx.x;
  int og=tid&7, pg=tid>>3, lloc=pg>>2, c0=og*8;
  float acc[8][4];
  t1_tile(sm, ws, P11, P40, b, pblk, tid, acc, og, pg, lloc, c0);
  __syncthreads();   // GEMM reads done -> overlay
  {
    int kg = pg&3;
    #pragma unroll
    for (int j=0;j<8;++j){
      float rs = acc[j][0]+acc[j][1]+acc[j][2]+acc[j][3];
      sm[(lloc*64 + c0 + j)*4 + kg] = rs;                 // lds_a [0,2048)
    }
    #pragma unroll
    for (int i=0;i<4;++i){
      int k = kg*4+i;
      #pragma unroll
      for (int j=0;j<8;++j)
        sm[2048 + (k*64 + c0 + j)*8 + lloc] = acc[j][i];  // lds_b [2048,10240)
    }
  }
  for (int t=tid;t<512;t+=256) sm[10240+t] = 2.0f*P22[(t&7)*64 + (t>>3)];  // [c*8+o2]
  if (tid<64) sm[10752+tid] = P42[tid];                                    // [o2*8+j]
  else if (tid<128){ int t2=tid-64; sm[10816+t2]=ws[OFF_S1+t2]; }
  else if (tid<192){ int t2=tid-128; sm[10880+t2]=ws[OFF_T1+t2]; }
  __syncthreads();
  for (int e=tid;e<512;e+=256){                  // M1L8 [10944,11456)
    float v = sm[e*4+0]+sm[e*4+1]+sm[e*4+2]+sm[e*4+3];
    sm[10944+e] = v*(1.f/16.f);
  }
  #pragma unroll
  for (int r=0;r<4;++r){                          // M1K partial [11456,12480)
    int e = tid + r*256;
    float v=0.f;
    #pragma unroll
    for (int ll=0; ll<8; ++ll) v += sm[2048 + e*8 + ll];
    sm[11456+e] = v*(1.f/64.f);
  }
  __syncthreads();
  if (tid<64){
    int l=tid>>3, o2=tid&7;
    float s=0.f;
    for (int c=0;c<64;++c){
      float mn = sm[10816+c]*sm[10944+l*64+c] + sm[10880+c];  // s1*M1L+t1
      s += sm[10240+c*8+o2]*mn;
    }
    float s2=0.f;
    #pragma unroll
    for (int j=0;j<8;++j) s2 += sm[10752+o2*8+j]*ws[OFF_HBL+((size_t)b*64+pblk*8+l)*8+j];
    ws[OFF_X2+((size_t)b*64+pblk*8+l)*8+o2] = s + 0.1f*s2;
  } else if (tid<192){
    int tt=tid-64, k=tt>>3, o2=tt&7;
    float s=0.f;
    for (int c=0;c<64;++c) s += sm[10240+c*8+o2]*sm[10816+c]*sm[11456+k*64+c];
    if (pblk==0){
      float ct=0.f;
      for (int c=0;c<64;++c) ct += sm[10240+c*8+o2]*sm[10880+c];
      float s2=0.f;
      #pragma unroll
      for (int j=0;j<8;++j) s2 += sm[10752+o2*8+j]*ws[OFF_HBK+((size_t)b*16+k)*8+j];
      s += ct + 0.1f*s2;
    }
    atomicAdd(&ws[OFF_Y2+((size_t)b*16+k)*8+o2], s);
  }
}

// K6: tile pass #3 + layer-2 + normalize + output (real part, f32).
__global__ __launch_bounds__(256) void k_final(const float* __restrict__ ws,
                                               const float* __restrict__ P11,
                                               const float* __restrict__ P40,
                                               const float* __restrict__ P12,
                                               float* __restrict__ out,
                                               long long out_cap, int interleaved){
  __shared__ float sm[9152];   // T1c [0,8512); W2l [8512,9024); s1 [9024); t1 [9088)
  int bid=blockIdx.x, b=bid>>3, pblk=bid&7, tid=threadIdx.x;
  int og=tid&7, pg=tid>>3, lloc=pg>>2, c0=og*8;
  for (int t=tid;t<512;t+=256) sm[8512+t] = 2.0f*P12[t];   // [o2*64+c]
  if (tid<64) sm[9024+tid]=ws[OFF_S1+tid];
  else if (tid<128) sm[9088+(tid-64)]=ws[OFF_T1+(tid-64)];
  float acc[8][4];
  t1_tile(sm, ws, P11, P40, b, pblk, tid, acc, og, pg, lloc, c0);
  __syncthreads();
  {
    int kg = pg&3;
    #pragma unroll
    for (int i=0;i<4;++i){
      int p = lloc*16 + kg*4 + i;
      #pragma unroll
      for (int j=0;j<8;++j) sm[(c0+j)*133 + p] = acc[j][i];  // T1c [c*133+p]
    }
  }
  __syncthreads();
  if (tid < 128){
    int p = tid, k = p & 15, lglob = pblk*8 + (p>>4);
    float a2[8];
    {
      const float* xp = ws + OFF_X2 + ((size_t)b*64+lglob)*8;
      const float* yp = ws + OFF_Y2 + ((size_t)b*16+k)*8;
      float4 x0_ = *(const float4*)&xp[0];
      float4 x1_ = *(const float4*)&xp[4];
      float4 y0_ = *(const float4*)&yp[0];
      float4 y1_ = *(const float4*)&yp[4];
      a2[0]=x0_.x+y0_.x; a2[1]=x0_.y+y0_.y; a2[2]=x0_.z+y0_.z; a2[3]=x0_.w+y0_.w;
      a2[4]=x1_.x+y1_.x; a2[5]=x1_.y+y1_.y; a2[6]=x1_.z+y1_.z; a2[7]=x1_.w+y1_.w;
    }
    for (int c=0;c<64;++c){
      float tn = sm[9024+c]*sm[c*133+p] + sm[9088+c];   // s1*T1+t1
      #pragma unroll
      for (int o2=0;o2<8;++o2) a2[o2] += sm[8512+o2*64+c]*tn;
    }
    float nrm=0.f;
    #pragma unroll
    for (int o2=0;o2<8;++o2) nrm += a2[o2]*a2[o2];
    float inv = 1.0f/sqrtf(nrm);
    size_t pos = (size_t)b*PPP + lglob*KKK + k;
    if (interleaved){
      long long idx = (long long)pos*8;
      if (idx+8 <= out_cap){
        *(float4*)&out[idx]   = make_float4(a2[0]*inv, a2[4]*inv, a2[1]*inv, a2[5]*inv);
        *(float4*)&out[idx+4] = make_float4(a2[2]*inv, a2[6]*inv, a2[3]*inv, a2[7]*inv);
      }
    } else {
      long long idx = (long long)pos*4;
      if (idx+4 <= out_cap)
        *(float4*)&out[idx] = make_float4(a2[0]*inv, a2[1]*inv, a2[2]*inv, a2[3]*inv);
    }
  }
}

extern "C" void kernel_launch(void* const* d_in, const int* in_sizes, int n_in,
                              void* d_out, int out_size, void* d_ws, size_t ws_size,
                              hipStream_t stream) {
  if (n_in < 15) return;
  if (in_sizes[0] != BRR*4096 || in_sizes[1] != BRR*4096) return;
  if (in_sizes[4] != 512)  return;   // P4_0 (64,8)
  if (in_sizes[7] != 4096) return;   // P1_1 (64,64)
  if (in_sizes[12] != 512) return;   // P1_2 (8,64)
  if (ws_size < (size_t)WS_FLOATS*4) return;   // clean fail, not a fault

  const float* Hr   = (const float*)d_in[0];
  const float* Hi   = (const float*)d_in[1];
  const float* P4_0 = (const float*)d_in[4];
  const float* g0   = (const float*)d_in[5];
  const float* b0   = (const float*)d_in[6];
  const float* P1_1 = (const float*)d_in[7];
  const float* P2_1 = (const float*)d_in[8];
  const float* P4_1 = (const float*)d_in[9];
  const float* g1   = (const float*)d_in[10];
  const float* b1   = (const float*)d_in[11];
  const float* P1_2 = (const float*)d_in[12];
  const float* P2_2 = (const float*)d_in[13];
  const float* P4_2 = (const float*)d_in[14];
  float* ws  = (float*)d_ws;
  float* out = (float*)d_out;
  int interleaved = (out_size >= 4194304) ? 1 : 0;

  k_zero<<<68, 256, 0, stream>>>((float4*)(ws + OFF_Y2), (65536+4096)/4);
  k_prep<<<BRR, 256, 0, stream>>>(Hr, Hi, P4_0, ws);
  k_bn<<<1, 64, 0, stream>>>(ws, g0, b0, OFF_SUM0, OFF_S0);
  k_xy1<<<2560, 256, 0, stream>>>(ws, P2_1, P4_1);
  k_stats1<<<BRR*8, 256, 0, stream>>>(ws, P1_1, P4_0);
  k_bn<<<1, 64, 0, stream>>>(ws, g1, b1, OFF_SUM1, OFF_S1);
  k_xy2<<<BRR*8, 256, 0, stream>>>(ws, P1_1, P4_0, P2_2, P4_2);
  k_final<<<BRR*8, 256, 0, stream>>>(ws, P1_1, P4_0, P1_2, out,
                                     (long long)out_size, interleaved);
}